// Round 8
// baseline (346.953 us; speedup 1.0000x reference)
//
#include <hip/hip_runtime.h>
#include <cmath>

#define TW 32
#define TH 48
#define HR (TH + 10)     // 58 rows of h-pass results
#define LSTRIDE 35       // padded LDS row stride (in half4 / half units)
#define IMG 512
#define SSIM_C1 1e-4f
#define SSIM_C2 9e-4f

struct GaussWin { float g[11]; };

typedef float v2f __attribute__((ext_vector_type(2)));
typedef _Float16 h4v __attribute__((ext_vector_type(4)));

// Native packed fp32 -> v_pk_fma_f32 / v_pk_mul_f32 (gfx90a+ HasPackedFP32Ops).
__device__ __forceinline__ v2f pk_fma(v2f a, v2f b, v2f c) {
    return __builtin_elementwise_fma(a, b, c);
}

// LDS: h-pass results compressed to f16 (one RNE rounding; phase-2 math back
// in f32). half4 row stride 35:
//  - 35 = 3 mod 16, so phase-1 b64 writes (16 lanes/cyc: r in {r0..r0+3},
//    cs in {0,8,16,24}) hit (3r+cs) mod 16 = {0,3,6,9}+{0,8} -- all distinct,
//    conflict-free; phase-2 b64 reads (3r+c, c consecutive) conflict-free.
//  - every LDS address is base + compile-time immediate (280*t / 70*t).
//  - 20.3 KB/block -> 7 blocks/CU (vs 4 at f32), and b64 halves LDS pipe
//    cycles vs b128.
__launch_bounds__(256, 7)
__global__ void ssim_tile_kernel(const float* __restrict__ x,
                                 const float* __restrict__ y,
                                 const float* __restrict__ conf,
                                 float* __restrict__ partials,
                                 float* __restrict__ out,
                                 int use_ws, float scale,
                                 GaussWin W) {
    __shared__ h4v      s_h4[HR * LSTRIDE];   // 16240 B (mu_x, mu_y, sxx, syy)
    __shared__ _Float16 s_h1[HR * LSTRIDE];   //  4060 B (sxy)
    __shared__ float    s_red[4];             // ~20.3 KB total -> 7 blocks/CU

    const int tid = threadIdx.x;
    const int plane = blockIdx.z;              // b*3 + c
    const int tx0 = blockIdx.x * TW;
    const int ty0 = blockIdx.y * TH;
    const int pbase = plane * (IMG * IMG);
    const int cbase = (plane / 3) * (IMG * IMG);

    // Gaussian symmetric: g[k] == g[10-k] bitwise. 6 distinct packed weights.
    constexpr int WI[11] = {0,1,2,3,4,5,4,3,2,1,0};
    v2f w2[6];
    #pragma unroll
    for (int i = 0; i < 6; i++) w2[i] = (v2f){W.g[i], W.g[i]};

    // Interior blocks touch no image border anywhere in the halo window.
    const bool interior = (blockIdx.x >= 1) & (blockIdx.x <= 14) &
                          (blockIdx.y >= 1) & (blockIdx.y <= 9);

    // ---- Phase 1: horizontal pass, direct from global ----
    // 58 rows x 4 col-groups = 232 strips, one per thread, one round.
    // Strip = 8 output cols; reads 6 aligned float4s per array covering cols
    // [cs-8, cs+16); elements 3..20 are the 18 taps. 16B-aligned reads are
    // fully in- or out-of-bounds -> exact zero padding.
    if (tid < HR * 4) {
        const int r = tid >> 2;
        const int cs = (tid & 3) * 8;
        const int gy = ty0 - 5 + r;
        const float* xrow = x + pbase + gy * IMG;
        const float* yrow = y + pbase + gy * IMG;
        const int c0 = tx0 + cs - 8;

        float4 fx[6], fy[6];
        if (interior) {
            #pragma unroll
            for (int q = 0; q < 6; q++) {
                fx[q] = *(const float4*)(xrow + c0 + 4 * q);
                fy[q] = *(const float4*)(yrow + c0 + 4 * q);
            }
        } else {
            const bool rowok = ((unsigned)gy < IMG);
            #pragma unroll
            for (int q = 0; q < 6; q++) {
                int col = c0 + 4 * q;
                fx[q] = make_float4(0.f, 0.f, 0.f, 0.f);
                fy[q] = make_float4(0.f, 0.f, 0.f, 0.f);
                if (rowok && (unsigned)col <= (unsigned)(IMG - 4)) {
                    fx[q] = *(const float4*)(xrow + col);
                    fy[q] = *(const float4*)(yrow + col);
                }
            }
        }
        float vxa[24], vya[24];
        #pragma unroll
        for (int q = 0; q < 6; q++) {
            vxa[4*q+0]=fx[q].x; vxa[4*q+1]=fx[q].y; vxa[4*q+2]=fx[q].z; vxa[4*q+3]=fx[q].w;
            vya[4*q+0]=fy[q].x; vya[4*q+1]=fy[q].y; vya[4*q+2]=fy[q].z; vya[4*q+3]=fy[q].w;
        }

        // Streaming tap-major conv.
        v2f amu[8], as2[8];
        float axy[8];
        #pragma unroll
        for (int j = 0; j < 8; j++) { amu[j]=(v2f){0.f,0.f}; as2[j]=(v2f){0.f,0.f}; axy[j]=0.f; }
        #pragma unroll
        for (int k = 0; k < 18; k++) {
            float xv = vxa[k + 3], yv = vya[k + 3];
            v2f xy = (v2f){xv, yv};
            v2f p2 = xy * xy;                 // (x^2, y^2) -> v_pk_mul_f32
            float pxy = xv * yv;
            const int jlo = (k - 10 > 0) ? (k - 10) : 0;
            const int jhi = (k < 7) ? k : 7;
            #pragma unroll
            for (int j = jlo; j <= jhi; j++) {
                v2f w = w2[WI[k - j]];
                amu[j] = pk_fma(xy, w, amu[j]);
                as2[j] = pk_fma(p2, w, as2[j]);
                axy[j] = fmaf(pxy, w.x, axy[j]);
            }
        }
        h4v*      h4p = &s_h4[r * LSTRIDE + cs];
        _Float16* h1p = &s_h1[r * LSTRIDE + cs];
        #pragma unroll
        for (int j = 0; j < 8; j++) {
            h4p[j] = (h4v){(_Float16)amu[j].x, (_Float16)amu[j].y,
                           (_Float16)as2[j].x, (_Float16)as2[j].y};
            h1p[j] = (_Float16)axy[j];
        }
    }

    // Prefetch conf (consumed in epilogue) before the barrier.
    const int c  = tid & 31;
    const int r0 = (tid >> 5) * 6;            // 8 groups x 6 rows = 48 rows
    float cf[6];
    #pragma unroll
    for (int j = 0; j < 6; j++) {
        int gy = ty0 + r0 + j;
        cf[j] = (gy < IMG) ? conf[cbase + gy * IMG + tx0 + c] : 0.f;
    }
    __syncthreads();

    // ---- Phase 2: vertical pass, 6 vertically-adjacent outputs per thread ----
    v2f amu[6], as2[6];
    float axy[6];
    #pragma unroll
    for (int j = 0; j < 6; j++) { amu[j]=(v2f){0.f,0.f}; as2[j]=(v2f){0.f,0.f}; axy[j]=0.f; }

    const h4v*      h4p = &s_h4[r0 * LSTRIDE + c];
    const _Float16* h1p = &s_h1[r0 * LSTRIDE + c];
    #pragma unroll
    for (int t = 0; t < 16; t++) {
        h4v  hv = h4p[t * LSTRIDE];           // ds_read_b64, imm offset 280*t
        float h1 = (float)h1p[t * LSTRIDE];   // ds_read_u16, imm offset 70*t
        v2f hmu = (v2f){(float)hv.x, (float)hv.y};
        v2f hs2 = (v2f){(float)hv.z, (float)hv.w};
        #pragma unroll
        for (int j = 0; j < 6; j++) {
            int k = t - j;                    // constant post-unroll
            if (k >= 0 && k <= 10) {
                v2f w = w2[WI[k]];
                amu[j] = pk_fma(hmu, w, amu[j]);
                as2[j] = pk_fma(hs2, w, as2[j]);
                axy[j] = fmaf(h1, w.x, axy[j]);
            }
        }
    }

    // ---- Epilogue: SSIM + conf weighting + accumulate ----
    // Out-of-image rows (by==10 tail) have cf==0 and finite loss (den>0),
    // so they contribute exactly 0 -- no branch needed.
    float lsum = 0.f;
    #pragma unroll
    for (int j = 0; j < 6; j++) {
        float mu_x = amu[j].x, mu_y = amu[j].y;
        float mu_x2 = mu_x * mu_x;
        float mu_y2 = mu_y * mu_y;
        float mu_xy = mu_x * mu_y;
        float sigx  = as2[j].x - mu_x2;
        float sigy  = as2[j].y - mu_y2;
        float sigxy = axy[j] - mu_xy;
        float num = (2.f * mu_xy + SSIM_C1) * (2.f * sigxy + SSIM_C2);
        float den = (mu_x2 + mu_y2 + SSIM_C1) * (sigx + sigy + SSIM_C2);
        float ssim = num * __builtin_amdgcn_rcpf(den);   // den >= C1*C2 > 0
        float loss = 1.f - ssim;
        loss = fminf(fmaxf(loss, 0.f), 1.f);
        lsum = fmaf(loss, cf[j], lsum);
    }

    // ---- Block reduction ----
    #pragma unroll
    for (int off = 32; off; off >>= 1) lsum += __shfl_down(lsum, off, 64);
    if ((tid & 63) == 0) s_red[tid >> 6] = lsum;
    __syncthreads();
    if (tid == 0) {
        float t = s_red[0] + s_red[1] + s_red[2] + s_red[3];
        if (use_ws) {
            partials[blockIdx.x + gridDim.x * (blockIdx.y + gridDim.y * blockIdx.z)] = t;
        } else {
            atomicAdd(out, t * scale);
        }
    }
}

// Single-block reduce: writes out[0] directly (no memset, no atomics).
__global__ void reduce_kernel(const float* __restrict__ partials, int n,
                              float* __restrict__ out, float scale) {
    __shared__ float s_red[16];
    float s = 0.f;
    const float4* p4 = (const float4*)partials;
    const int n4 = n >> 2;
    for (int i = threadIdx.x; i < n4; i += 1024) {
        float4 v = p4[i];
        s += (v.x + v.y) + (v.z + v.w);
    }
    for (int i = (n4 << 2) + threadIdx.x; i < n; i += 1024) s += partials[i];
    #pragma unroll
    for (int off = 32; off; off >>= 1) s += __shfl_down(s, off, 64);
    if ((threadIdx.x & 63) == 0) s_red[threadIdx.x >> 6] = s;
    __syncthreads();
    if (threadIdx.x == 0) {
        float t = 0.f;
        #pragma unroll
        for (int i = 0; i < 16; i++) t += s_red[i];
        out[0] = t * scale;
    }
}

extern "C" void kernel_launch(void* const* d_in, const int* in_sizes, int n_in,
                              void* d_out, int out_size, void* d_ws, size_t ws_size,
                              hipStream_t stream) {
    const float* x    = (const float*)d_in[0];
    const float* y    = (const float*)d_in[1];
    const float* conf = (const float*)d_in[2];
    float* out = (float*)d_out;
    float* partials = (float*)d_ws;

    // Gaussian window, computed like the reference: float64 exp + normalize, cast f32
    GaussWin W;
    {
        double gd[11], s = 0.0;
        for (int i = 0; i < 11; i++) { gd[i] = exp(-((i - 5) * (i - 5)) / 4.5); s += gd[i]; }
        for (int i = 0; i < 11; i++) W.g[i] = (float)(gd[i] / s);
    }

    const int B = 16, C = 3;
    const float scale = 1.0f / (float)(B * C * IMG * IMG);
    const int gy_blocks = (IMG + TH - 1) / TH;              // 11 (last block masked)
    dim3 grid(IMG / TW, gy_blocks, B * C);                  // 16 x 11 x 48 = 8448 blocks
    const int nblocks = (IMG / TW) * gy_blocks * B * C;
    const int use_ws = (ws_size >= (size_t)nblocks * sizeof(float)) ? 1 : 0;

    if (!use_ws) {
        // fallback: atomic accumulation into d_out (poisoned before each call)
        hipMemsetAsync(d_out, 0, sizeof(float), stream);
    }
    ssim_tile_kernel<<<grid, 256, 0, stream>>>(x, y, conf, partials, out, use_ws, scale, W);
    if (use_ws) {
        reduce_kernel<<<1, 1024, 0, stream>>>(partials, nblocks, out, scale);
    }
}